// Round 1
// baseline (141.228 us; speedup 1.0000x reference)
//
#include <hip/hip_runtime.h>

// COLMAP-style reprojection residual:
//   cam = pose[ci] (10f: t[3], q[4], f, k1, k2); p = points_3d[pi]
//   q normalized; p_cam = p + 2*qv x (qv x p + qw*p) + t
//   uvp = p_cam.xy / p_cam.z; n=|uvp|^2; d=1+k1 n+k2 n^2
//   out = uvp*d*f - points_2d
// Memory-bound: 192 MB streaming + cached gathers. One thread per obs.

__global__ __launch_bounds__(256) void reproj_kernel(
    const float2* __restrict__ p2d,
    const int* __restrict__ cidx,
    const int* __restrict__ pidx,
    const float* __restrict__ pose,
    const float* __restrict__ pts3,
    float2* __restrict__ out,
    int M)
{
    int i = blockIdx.x * blockDim.x + threadIdx.x;
    if (i >= M) return;

    int ci = cidx[i];
    int pi = pidx[i];

    const float* cam = pose + (long)ci * 10;
    float tx = cam[0], ty = cam[1], tz = cam[2];
    float qx = cam[3], qy = cam[4], qz = cam[5], qw = cam[6];
    float f  = cam[7], k1 = cam[8], k2 = cam[9];

    float inv = rsqrtf(qx*qx + qy*qy + qz*qz + qw*qw);
    qx *= inv; qy *= inv; qz *= inv; qw *= inv;

    const float* pp = pts3 + (long)pi * 3;
    float px = pp[0], py = pp[1], pz = pp[2];

    // uv = qv x p
    float ux = qy*pz - qz*py;
    float uy = qz*px - qx*pz;
    float uz = qx*py - qy*px;
    // w = uv + qw*p
    float wx = ux + qw*px;
    float wy = uy + qw*py;
    float wz = uz + qw*pz;
    // c = qv x w
    float cx = qy*wz - qz*wy;
    float cy = qz*wx - qx*wz;
    float cz = qx*wy - qy*wx;

    float Px = px + 2.0f*cx + tx;
    float Py = py + 2.0f*cy + ty;
    float Pz = pz + 2.0f*cz + tz;

    float invz = 1.0f / Pz;
    float u = Px * invz;
    float v = Py * invz;

    float n = u*u + v*v;
    float d = 1.0f + k1*n + k2*n*n;
    float s = d * f;

    float2 o = p2d[i];
    out[i] = make_float2(u*s - o.x, v*s - o.y);
}

extern "C" void kernel_launch(void* const* d_in, const int* in_sizes, int n_in,
                              void* d_out, int out_size, void* d_ws, size_t ws_size,
                              hipStream_t stream) {
    const float2* p2d  = (const float2*)d_in[0];
    const int*    cidx = (const int*)d_in[1];
    const int*    pidx = (const int*)d_in[2];
    const float*  pose = (const float*)d_in[3];
    const float*  pts3 = (const float*)d_in[4];
    float2*       out  = (float2*)d_out;

    int M = in_sizes[1];  // camera_indices count = number of observations

    int block = 256;
    int grid = (M + block - 1) / block;
    reproj_kernel<<<grid, block, 0, stream>>>(p2d, cidx, pidx, pose, pts3, out, M);
}